// Round 8
// baseline (1377.233 us; speedup 1.0000x reference)
//
#include <hip/hip_runtime.h>

#define T_TOK 1024
#define D_HID 2048
#define NEXP 32
#define I_EXP 1408
#define TOPK 6
#define NGRP 8
#define GSIZE 4
#define TOPG 3
#define SHI 2816
#define RSCALE 2.5f

typedef __attribute__((ext_vector_type(8))) short short8;
typedef __attribute__((ext_vector_type(4))) float floatx4;

__device__ __forceinline__ unsigned short f2b(float f) {
  unsigned int u = __float_as_uint(f);
  u += 0x7fffu + ((u >> 16) & 1u);   // RNE
  return (unsigned short)(u >> 16);
}

__device__ __forceinline__ float b2f(unsigned short s) {
  return __uint_as_float((unsigned)s << 16);
}

__device__ __forceinline__ short8 pack8s(const float* v) {
  union { uint4 u; short8 s; } o;
  o.u.x = (unsigned)f2b(v[0]) | ((unsigned)f2b(v[1]) << 16);
  o.u.y = (unsigned)f2b(v[2]) | ((unsigned)f2b(v[3]) << 16);
  o.u.z = (unsigned)f2b(v[4]) | ((unsigned)f2b(v[5]) << 16);
  o.u.w = (unsigned)f2b(v[6]) | ((unsigned)f2b(v[7]) << 16);
  return o.s;
}

// ---------------- routing: one block (1 wave) per token ----------------
__global__ __launch_bounds__(64) void k_route(
    const float* __restrict__ x, const float* __restrict__ gw,
    const float* __restrict__ bias, int* __restrict__ tki, float* __restrict__ tkw)
{
  int t = blockIdx.x;
  __shared__ float xs[D_HID];
  __shared__ float sc[NEXP], cor[NEXP];
  int lane = threadIdx.x;
  for (int d = lane * 4; d < D_HID; d += 64 * 4)
    *(float4*)(xs + d) = *(const float4*)(x + (size_t)t * D_HID + d);
  __syncthreads();
  if (lane < NEXP) {
    float acc = 0.f;
    for (int d = 0; d < D_HID; ++d) acc += xs[d] * gw[d * NEXP + lane];
    float s = 1.f / (1.f + expf(-acc));
    sc[lane] = s;
    cor[lane] = s + bias[lane];
  }
  __syncthreads();
  if (lane == 0) {
    float gs[NGRP];
    for (int g = 0; g < NGRP; ++g) {
      float m1 = -INFINITY, m2 = -INFINITY;
      for (int j = 0; j < GSIZE; ++j) {
        float v = cor[g * GSIZE + j];
        if (v > m1) { m2 = m1; m1 = v; } else if (v > m2) m2 = v;
      }
      gs[g] = m1 + m2;
    }
    unsigned gmask = 0;
    for (int rr = 0; rr < TOPG; ++rr) {
      int bi = -1; float bv = -INFINITY;
      for (int g = 0; g < NGRP; ++g)
        if (!((gmask >> g) & 1) && gs[g] > bv) { bv = gs[g]; bi = g; }
      gmask |= 1u << bi;
    }
    unsigned used = 0;
    float wsum = 0.f;
    int idxs[TOPK]; float wsel[TOPK];
    for (int rr = 0; rr < TOPK; ++rr) {
      int bi = -1; float bv = -INFINITY;
      for (int e = 0; e < NEXP; ++e) {
        if (!((gmask >> (e / GSIZE)) & 1)) continue;
        if ((used >> e) & 1) continue;
        if (cor[e] > bv) { bv = cor[e]; bi = e; }
      }
      used |= 1u << bi;
      idxs[rr] = bi; wsel[rr] = sc[bi]; wsum += sc[bi];
    }
    float inv = 1.f / (wsum + 1e-20f);
    for (int rr = 0; rr < TOPK; ++rr) {
      tki[t * TOPK + rr] = idxs[rr];
      tkw[t * TOPK + rr] = wsel[rr] * inv;
    }
  }
}

// ---------------- counts + offsets (single block) ----------------
__global__ __launch_bounds__(256) void k_count(const int* __restrict__ tki,
                                               int* __restrict__ cnt, int* __restrict__ offp)
{
  __shared__ int c[NEXP];
  if (threadIdx.x < NEXP) c[threadIdx.x] = 0;
  __syncthreads();
  for (int i = threadIdx.x; i < T_TOK * TOPK; i += 256) atomicAdd(&c[tki[i]], 1);
  __syncthreads();
  if (threadIdx.x == 0) {
    int s = 0;
    for (int e = 0; e < NEXP; ++e) { offp[e] = s; cnt[e] = c[e]; s += c[e]; }
    offp[NEXP] = s;
  }
}

// ---------------- deterministic compaction: one wave per expert ----------------
__global__ __launch_bounds__(64) void k_compact(
    const int* __restrict__ tki, const float* __restrict__ tkw,
    const int* __restrict__ offp, int* __restrict__ tok, float* __restrict__ wts)
{
  int e = blockIdx.x, lane = threadIdx.x;
  int base = offp[e];
  for (int t0 = 0; t0 < T_TOK; t0 += 64) {
    int t = t0 + lane;
    int found = -1;
    for (int j = 0; j < TOPK; ++j)
      if (tki[t * TOPK + j] == e) found = j;
    unsigned long long m = __ballot(found >= 0);
    if (found >= 0) {
      int pos = base + __popcll(m & ((1ull << lane) - 1ull));
      tok[pos] = t;
      wts[pos] = tkw[t * TOPK + found];
    }
    base += __popcll(m);
  }
}

// ---------------- fp32 -> bf16 cast of hidden states ----------------
__global__ __launch_bounds__(256) void k_cast(const float* __restrict__ x,
                                              unsigned short* __restrict__ xb, int n4)
{
  int i = blockIdx.x * 256 + threadIdx.x;
  if (i < n4) {
    float4 v = ((const float4*)x)[i];
    ushort4 o;
    o.x = f2b(v.x); o.y = f2b(v.y); o.z = f2b(v.z); o.w = f2b(v.w);
    ((ushort4*)xb)[i] = o;
  }
}

// =================================================================
// Barrier-free streaming GEMM.  256 thr = 4 waves M-stacked.
// Block tile 256m x 32n; wave tile 64m x 32n (4mf x 2nf, acc=32/thread).
// A (bf16, L2-resident): direct dwordx4 fragment loads.
// B (fp32 weights, HBM stream): 16 coalesced dword loads/step, f2b packed
// in-register.  No LDS, no __syncthreads -> no vmcnt(0) drains; latency
// hidden purely by wave TLP (~16 waves/CU, ~5KB in flight each).
// =================================================================

template<int KD, bool FUSE>
__device__ __forceinline__ void gemm_pre(
    const unsigned short* __restrict__ Ab,
    const int* __restrict__ tok, int rowbase, int nrows,
    const float* __restrict__ B, int N,
    const unsigned short* __restrict__ Gp,
    unsigned short* __restrict__ O, int n0)
{
  const int tid = threadIdx.x;
  const int w = tid >> 6, lane = tid & 63;
  const int c = lane & 15, r = lane >> 4;
  const float* bp0 = B + (size_t)(r * 8) * N + n0 + c;
  const float* bp1 = bp0 + 16;

  for (int m0 = 0; m0 < nrows; m0 += 256) {
    const unsigned short* ap[4];
    #pragma unroll
    for (int mf = 0; mf < 4; ++mf) {
      int rl = min(m0 + w * 64 + mf * 16 + c, nrows - 1);
      int ta = tok ? tok[rowbase + rl] : (rowbase + rl);
      ap[mf] = Ab + (size_t)ta * KD + r * 8;
    }

    floatx4 acc[4][2] = {};

    #pragma unroll 1
    for (int kt = 0; kt < KD / 32; ++kt) {
      float b0[8], b1[8];
      #pragma unroll
      for (int j = 0; j < 8; ++j) b0[j] = bp0[(size_t)(kt * 32 + j) * N];
      #pragma unroll
      for (int j = 0; j < 8; ++j) b1[j] = bp1[(size_t)(kt * 32 + j) * N];
      short8 af[4];
      #pragma unroll
      for (int mf = 0; mf < 4; ++mf)
        af[mf] = *(const short8*)(ap[mf] + kt * 32);
      short8 f0 = pack8s(b0), f1 = pack8s(b1);
      #pragma unroll
      for (int mf = 0; mf < 4; ++mf) {
        acc[mf][0] = __builtin_amdgcn_mfma_f32_16x16x32_bf16(af[mf], f0, acc[mf][0], 0, 0, 0);
        acc[mf][1] = __builtin_amdgcn_mfma_f32_16x16x32_bf16(af[mf], f1, acc[mf][1], 0, 0, 0);
      }
    }

    #pragma unroll
    for (int mf = 0; mf < 4; ++mf)
      #pragma unroll
      for (int nf = 0; nf < 2; ++nf)
        #pragma unroll
        for (int v = 0; v < 4; ++v) {
          int rr = w * 64 + mf * 16 + r * 4 + v;
          if (m0 + rr < nrows) {
            size_t oi = (size_t)(rowbase + m0 + rr) * N + n0 + nf * 16 + c;
            float a = acc[mf][nf][v];
            if (FUSE) {
              float g = b2f(Gp[oi]);
              float s = g / (1.f + __expf(-g));
              O[oi] = f2b(s * a);
            } else {
              O[oi] = f2b(a);
            }
          }
        }
  }
}

template<int KD>
__device__ __forceinline__ void gemm_dn2(
    const unsigned short* __restrict__ Ab,   // compacted rows, lda = KD
    int rowbase, int nrows,
    const float* __restrict__ B, int N,
    const int* __restrict__ tok, const float* __restrict__ wts, float scale,
    float* __restrict__ out, int n0)
{
  const int tid = threadIdx.x;
  const int w = tid >> 6, lane = tid & 63;
  const int c = lane & 15, r = lane >> 4;
  const float* bp0 = B + (size_t)(r * 8) * N + n0 + c;
  const float* bp1 = bp0 + 16;

  for (int m0 = 0; m0 < nrows; m0 += 256) {
    const unsigned short* ap[4];
    #pragma unroll
    for (int mf = 0; mf < 4; ++mf) {
      int rl = min(m0 + w * 64 + mf * 16 + c, nrows - 1);
      ap[mf] = Ab + (size_t)(rowbase + rl) * KD + r * 8;
    }

    floatx4 acc[4][2] = {};

    #pragma unroll 1
    for (int kt = 0; kt < KD / 32; ++kt) {
      float b0[8], b1[8];
      #pragma unroll
      for (int j = 0; j < 8; ++j) b0[j] = bp0[(size_t)(kt * 32 + j) * N];
      #pragma unroll
      for (int j = 0; j < 8; ++j) b1[j] = bp1[(size_t)(kt * 32 + j) * N];
      short8 af[4];
      #pragma unroll
      for (int mf = 0; mf < 4; ++mf)
        af[mf] = *(const short8*)(ap[mf] + kt * 32);
      short8 f0 = pack8s(b0), f1 = pack8s(b1);
      #pragma unroll
      for (int mf = 0; mf < 4; ++mf) {
        acc[mf][0] = __builtin_amdgcn_mfma_f32_16x16x32_bf16(af[mf], f0, acc[mf][0], 0, 0, 0);
        acc[mf][1] = __builtin_amdgcn_mfma_f32_16x16x32_bf16(af[mf], f1, acc[mf][1], 0, 0, 0);
      }
    }

    #pragma unroll
    for (int mf = 0; mf < 4; ++mf)
      #pragma unroll
      for (int nf = 0; nf < 2; ++nf)
        #pragma unroll
        for (int v = 0; v < 4; ++v) {
          int rr = w * 64 + mf * 16 + r * 4 + v;
          if (m0 + rr < nrows) {
            int grow = rowbase + m0 + rr;
            int tk = tok ? tok[grow] : grow;
            float wgt = wts ? wts[grow] * scale : scale;
            atomicAdd(&out[(size_t)tk * N + n0 + nf * 16 + c], wgt * acc[mf][nf][v]);
          }
        }
  }
}

// grid.y: 0..31 routed experts, 32..35 shared 256-row chunks
__global__ __launch_bounds__(256, 4) void k_gate(
    const unsigned short* __restrict__ xb,
    const float* __restrict__ wg, const float* __restrict__ wsg,
    const int* __restrict__ offp, const int* __restrict__ cnt,
    const int* __restrict__ tok,
    unsigned short* __restrict__ gR, unsigned short* __restrict__ gS)
{
  const int ey = blockIdx.y, n0 = blockIdx.x * 32;
  if (ey < NEXP) {
    if (n0 >= I_EXP) return;
    int rb = offp[ey], nr = cnt[ey];
    if (nr <= 0) return;
    gemm_pre<D_HID, false>(xb, tok, rb, nr, wg + (size_t)ey * D_HID * I_EXP,
                           I_EXP, nullptr, gR, n0);
  } else {
    gemm_pre<D_HID, false>(xb, nullptr, (ey - NEXP) * 256, 256, wsg, SHI,
                           nullptr, gS, n0);
  }
}

__global__ __launch_bounds__(256, 4) void k_up(
    const unsigned short* __restrict__ xb,
    const float* __restrict__ wu, const float* __restrict__ wsu,
    const int* __restrict__ offp, const int* __restrict__ cnt,
    const int* __restrict__ tok,
    const unsigned short* __restrict__ gR, const unsigned short* __restrict__ gS,
    unsigned short* __restrict__ hR, unsigned short* __restrict__ hS)
{
  const int ey = blockIdx.y, n0 = blockIdx.x * 32;
  if (ey < NEXP) {
    if (n0 >= I_EXP) return;
    int rb = offp[ey], nr = cnt[ey];
    if (nr <= 0) return;
    gemm_pre<D_HID, true>(xb, tok, rb, nr, wu + (size_t)ey * D_HID * I_EXP,
                          I_EXP, gR, hR, n0);
  } else {
    gemm_pre<D_HID, true>(xb, nullptr, (ey - NEXP) * 256, 256, wsu, SHI,
                          gS, hS, n0);
  }
}

__global__ __launch_bounds__(256, 4) void k_down7(
    const unsigned short* __restrict__ hR, const unsigned short* __restrict__ hS,
    const float* __restrict__ wd, const float* __restrict__ wsd,
    const int* __restrict__ offp, const int* __restrict__ cnt,
    const int* __restrict__ tok, const float* __restrict__ wts,
    float* __restrict__ out)
{
  const int ey = blockIdx.y, n0 = blockIdx.x * 32;
  if (ey < NEXP) {
    int rb = offp[ey], nr = cnt[ey];
    if (nr <= 0) return;
    gemm_dn2<I_EXP>(hR, rb, nr, wd + (size_t)ey * I_EXP * D_HID, D_HID,
                    tok, wts, RSCALE, out, n0);
  } else {
    gemm_dn2<SHI>(hS, (ey - NEXP) * 256, 256, wsd, D_HID,
                  nullptr, nullptr, 1.0f, out, n0);
  }
}

extern "C" void kernel_launch(void* const* d_in, const int* in_sizes, int n_in,
                              void* d_out, int out_size, void* d_ws, size_t ws_size,
                              hipStream_t stream) {
  const float* x    = (const float*)d_in[0];
  const float* gw   = (const float*)d_in[1];
  const float* bias = (const float*)d_in[2];
  const float* wg   = (const float*)d_in[3];
  const float* wu   = (const float*)d_in[4];
  const float* wd   = (const float*)d_in[5];
  const float* wsg  = (const float*)d_in[6];
  const float* wsu  = (const float*)d_in[7];
  const float* wsd  = (const float*)d_in[8];
  float* out = (float*)d_out;

  char* ws = (char*)d_ws;
  size_t o = 0;
  auto take = [&](size_t bytes) {
    char* p = ws + o;
    o += (bytes + 255) & ~(size_t)255;
    return p;
  };
  int*   tki  = (int*)  take((size_t)T_TOK * TOPK * 4);
  float* tkw  = (float*)take((size_t)T_TOK * TOPK * 4);
  int*   cnt  = (int*)  take(NEXP * 4);
  int*   offp = (int*)  take((NEXP + 1) * 4);
  int*   tok  = (int*)  take((size_t)T_TOK * TOPK * 4);
  float* wts  = (float*)take((size_t)T_TOK * TOPK * 4);
  unsigned short* xb = (unsigned short*)take((size_t)T_TOK * D_HID * 2);
  unsigned short* gR = (unsigned short*)take((size_t)T_TOK * TOPK * I_EXP * 2);
  unsigned short* gS = (unsigned short*)take((size_t)T_TOK * SHI * 2);
  unsigned short* hR = (unsigned short*)take((size_t)T_TOK * TOPK * I_EXP * 2);
  unsigned short* hS = (unsigned short*)take((size_t)T_TOK * SHI * 2);

  (void)hipMemsetAsync(out, 0, (size_t)T_TOK * D_HID * sizeof(float), stream);
  k_route<<<T_TOK, 64, 0, stream>>>(x, gw, bias, tki, tkw);
  k_count<<<1, 256, 0, stream>>>(tki, cnt, offp);
  k_compact<<<NEXP, 64, 0, stream>>>(tki, tkw, offp, tok, wts);
  k_cast<<<(T_TOK * D_HID / 4 + 255) / 256, 256, 0, stream>>>(x, xb, T_TOK * D_HID / 4);

  // gate pass: preacts
  k_gate<<<dim3(SHI / 32, NEXP + 4), 256, 0, stream>>>(
      xb, wg, wsg, offp, cnt, tok, gR, gS);
  // up pass + fused silu(g)*u epilogue
  k_up<<<dim3(SHI / 32, NEXP + 4), 256, 0, stream>>>(
      xb, wu, wsu, offp, cnt, tok, gR, gS, hR, hS);
  // down: weighted atomic scatter (routed) + shared
  k_down7<<<dim3(D_HID / 32, NEXP + 4), 256, 0, stream>>>(
      hR, hS, wd, wsd, offp, cnt, tok, wts, out);
}

// Round 9
// 1004.121 us; speedup vs baseline: 1.3716x; 1.3716x over previous
//
#include <hip/hip_runtime.h>

#define T_TOK 1024
#define D_HID 2048
#define NEXP 32
#define I_EXP 1408
#define TOPK 6
#define NGRP 8
#define GSIZE 4
#define TOPG 3
#define SHI 2816
#define RSCALE 2.5f

typedef __attribute__((ext_vector_type(8))) short short8;
typedef __attribute__((ext_vector_type(4))) float floatx4;

__device__ __forceinline__ unsigned short f2b(float f) {
  unsigned int u = __float_as_uint(f);
  u += 0x7fffu + ((u >> 16) & 1u);   // RNE
  return (unsigned short)(u >> 16);
}

__device__ __forceinline__ void gld_lds16(const void* g, void* l) {
  __builtin_amdgcn_global_load_lds(
      (const __attribute__((address_space(1))) unsigned int*)g,
      (__attribute__((address_space(3))) unsigned int*)l, 16, 0, 0);
}

__device__ __forceinline__ uint4 pack8(const float* v) {
  uint4 o;
  o.x = (unsigned)f2b(v[0]) | ((unsigned)f2b(v[1]) << 16);
  o.y = (unsigned)f2b(v[2]) | ((unsigned)f2b(v[3]) << 16);
  o.z = (unsigned)f2b(v[4]) | ((unsigned)f2b(v[5]) << 16);
  o.w = (unsigned)f2b(v[6]) | ((unsigned)f2b(v[7]) << 16);
  return o;
}

__device__ __forceinline__ uint2 pack4(const float* v) {
  uint2 o;
  o.x = (unsigned)f2b(v[0]) | ((unsigned)f2b(v[1]) << 16);
  o.y = (unsigned)f2b(v[2]) | ((unsigned)f2b(v[3]) << 16);
  return o;
}

// ---------------- routing: one block (1 wave) per token ----------------
__global__ __launch_bounds__(64) void k_route(
    const float* __restrict__ x, const float* __restrict__ gw,
    const float* __restrict__ bias, int* __restrict__ tki, float* __restrict__ tkw)
{
  int t = blockIdx.x;
  __shared__ float xs[D_HID];
  __shared__ float sc[NEXP], cor[NEXP];
  int lane = threadIdx.x;
  for (int d = lane * 4; d < D_HID; d += 64 * 4)
    *(float4*)(xs + d) = *(const float4*)(x + (size_t)t * D_HID + d);
  __syncthreads();
  if (lane < NEXP) {
    float acc = 0.f;
    for (int d = 0; d < D_HID; ++d) acc += xs[d] * gw[d * NEXP + lane];
    float s = 1.f / (1.f + expf(-acc));
    sc[lane] = s;
    cor[lane] = s + bias[lane];
  }
  __syncthreads();
  if (lane == 0) {
    float gs[NGRP];
    for (int g = 0; g < NGRP; ++g) {
      float m1 = -INFINITY, m2 = -INFINITY;
      for (int j = 0; j < GSIZE; ++j) {
        float v = cor[g * GSIZE + j];
        if (v > m1) { m2 = m1; m1 = v; } else if (v > m2) m2 = v;
      }
      gs[g] = m1 + m2;
    }
    unsigned gmask = 0;
    for (int rr = 0; rr < TOPG; ++rr) {
      int bi = -1; float bv = -INFINITY;
      for (int g = 0; g < NGRP; ++g)
        if (!((gmask >> g) & 1) && gs[g] > bv) { bv = gs[g]; bi = g; }
      gmask |= 1u << bi;
    }
    unsigned used = 0;
    float wsum = 0.f;
    int idxs[TOPK]; float wsel[TOPK];
    for (int rr = 0; rr < TOPK; ++rr) {
      int bi = -1; float bv = -INFINITY;
      for (int e = 0; e < NEXP; ++e) {
        if (!((gmask >> (e / GSIZE)) & 1)) continue;
        if ((used >> e) & 1) continue;
        if (cor[e] > bv) { bv = cor[e]; bi = e; }
      }
      used |= 1u << bi;
      idxs[rr] = bi; wsel[rr] = sc[bi]; wsum += sc[bi];
    }
    float inv = 1.f / (wsum + 1e-20f);
    for (int rr = 0; rr < TOPK; ++rr) {
      tki[t * TOPK + rr] = idxs[rr];
      tkw[t * TOPK + rr] = wsel[rr] * inv;
    }
  }
}

// ---------------- counts + offsets + padded offsets ----------------
__global__ __launch_bounds__(256) void k_count(const int* __restrict__ tki,
                                               int* __restrict__ cnt, int* __restrict__ offp,
                                               int* __restrict__ poff)
{
  __shared__ int c[NEXP];
  if (threadIdx.x < NEXP) c[threadIdx.x] = 0;
  __syncthreads();
  for (int i = threadIdx.x; i < T_TOK * TOPK; i += 256) atomicAdd(&c[tki[i]], 1);
  __syncthreads();
  if (threadIdx.x == 0) {
    int s = 0, p = 0;
    for (int e = 0; e < NEXP; ++e) {
      offp[e] = s; cnt[e] = c[e]; poff[e] = p;
      s += c[e];
      p += 256 * ((c[e] + 255) / 256);
    }
    offp[NEXP] = s; poff[NEXP] = p;
  }
}

// ---------------- deterministic compaction: one wave per expert ----------------
__global__ __launch_bounds__(64) void k_compact(
    const int* __restrict__ tki, const float* __restrict__ tkw,
    const int* __restrict__ offp, int* __restrict__ tok, float* __restrict__ wts)
{
  int e = blockIdx.x, lane = threadIdx.x;
  int base = offp[e];
  for (int t0 = 0; t0 < T_TOK; t0 += 64) {
    int t = t0 + lane;
    int found = -1;
    for (int j = 0; j < TOPK; ++j)
      if (tki[t * TOPK + j] == e) found = j;
    unsigned long long m = __ballot(found >= 0);
    if (found >= 0) {
      int pos = base + __popcll(m & ((1ull << lane) - 1ull));
      tok[pos] = t;
      wts[pos] = tkw[t * TOPK + found];
    }
    base += __popcll(m);
  }
}

// ---------------- tile-linear A prep (gather + fp32->bf16 cast) ----------------
// Layout per 256-row chunk: [kt][granule g = koff*256 + m] of 16B (8 bf16 along k).
// grid (NEXP+1, 4); y = chunk.  ey==NEXP -> shared (identity rows) into ApS.
__global__ __launch_bounds__(256) void k_prep(
    const float* __restrict__ x,
    const int* __restrict__ offp, const int* __restrict__ cnt,
    const int* __restrict__ poff, const int* __restrict__ tok,
    unsigned short* __restrict__ Ap, unsigned short* __restrict__ ApS)
{
  const int ey = blockIdx.x, ch = blockIdx.y, m = threadIdx.x;
  const int* tk = nullptr;
  int nr;
  unsigned short* dst;
  if (ey < NEXP) {
    nr = cnt[ey];
    int pad = poff[ey + 1] - poff[ey];
    if (ch * 256 >= pad) return;
    dst = Ap + ((size_t)(poff[ey] >> 8) + ch) * 64 * 8192;
    tk = tok + offp[ey];
  } else {
    nr = T_TOK;
    dst = ApS + (size_t)ch * 64 * 8192;
  }
  int grow = ch * 256 + m;
  const float* src = nullptr;
  if (grow < nr) {
    int t = tk ? tk[grow] : grow;
    src = x + (size_t)t * D_HID;
  }
  for (int kt = 0; kt < 64; ++kt) {
    #pragma unroll
    for (int ko = 0; ko < 4; ++ko) {
      uint4 w = {0u, 0u, 0u, 0u};
      if (src) {
        const float* s = src + kt * 32 + ko * 8;
        float4 a = *(const float4*)s;
        float4 b = *(const float4*)(s + 4);
        w.x = (unsigned)f2b(a.x) | ((unsigned)f2b(a.y) << 16);
        w.y = (unsigned)f2b(a.z) | ((unsigned)f2b(a.w) << 16);
        w.z = (unsigned)f2b(b.x) | ((unsigned)f2b(b.y) << 16);
        w.w = (unsigned)f2b(b.z) | ((unsigned)f2b(b.w) << 16);
      }
      *(uint4*)(dst + (size_t)kt * 8192 + (ko * 256 + m) * 8) = w;
    }
  }
}

// =================================================================
// GEMM bodies.  512 thr / 8 waves (4M x 2N), tile 256m x 64n, BK=32,
// double-buffered LDS, compiler-scheduled depth-1 (__syncthreads).
// A: CONTIGUOUS tile-linear source -> 2x gld_lds dwordx4 per thread
//    (8 lines/instr; the line-transaction fix).
// B: per-thread coalesced k-run, [n][k] pad 36 (0 conflicts, verified R5/R7).
// =================================================================

template<int N, int NKT_H>
__device__ __forceinline__ void gu_body(
    const unsigned short* __restrict__ Abase,    // chunk stride 64*8192 ushorts
    const float* __restrict__ wgp, const float* __restrict__ wup,
    unsigned short* __restrict__ hbase,          // chunk stride NKT_H*8192 ushorts
    int c0, int c1, int nrows, int n0,
    unsigned short* As, unsigned short* Bls)
{
  const int tid = threadIdx.x;
  const int wid = tid >> 6, lane = tid & 63;
  const int c = lane & 15, r = lane >> 4;
  const int wr = wid >> 1, wc = wid & 1;

  const int mat = wid >> 2;          // 0=gate, 1=up
  const int bko = wid & 3;
  const float* bsrc = (mat ? wup : wgp) + (size_t)(bko * 8) * N + n0 + lane;
  const int bwoff = lane * 36 + bko * 8 + mat * 2304;

  int aoff[4];
  #pragma unroll
  for (int mf = 0; mf < 4; ++mf)
    aoff[mf] = (r * 256 + wr * 64 + mf * 16 + c) * 8;
  int boff[2];
  #pragma unroll
  for (int nf = 0; nf < 2; ++nf)
    boff[nf] = (wc * 32 + nf * 16 + c) * 36 + r * 8;

  for (int ch = c0; ch < c1; ++ch) {
    const unsigned short* Ach = Abase + (size_t)ch * 64 * 8192;

    floatx4 accg[4][2] = {};
    floatx4 accu[4][2] = {};
    float br[8];

    #pragma unroll
    for (int j = 0; j < 8; ++j) br[j] = bsrc[(size_t)j * N];
    { uint4 pw = pack8(br); *(uint4*)&Bls[bwoff] = pw; }
    gld_lds16(Ach + tid * 8, As + tid * 8);
    gld_lds16(Ach + (512 + tid) * 8, As + (512 + tid) * 8);
    #pragma unroll
    for (int j = 0; j < 8; ++j) br[j] = bsrc[(size_t)(32 + j) * N];
    __syncthreads();

    int b = 0;
    for (int kt = 0; kt < 64; ++kt) {
      if (kt + 1 < 64) {
        { uint4 pw = pack8(br); *(uint4*)&Bls[(b ^ 1) * 4608 + bwoff] = pw; }
        const unsigned short* Ak = Ach + (size_t)(kt + 1) * 8192;
        gld_lds16(Ak + tid * 8, As + (b ^ 1) * 8192 + tid * 8);
        gld_lds16(Ak + (512 + tid) * 8, As + (b ^ 1) * 8192 + (512 + tid) * 8);
      }
      if (kt + 2 < 64) {
        const float* bs = bsrc + (size_t)(kt + 2) * 32 * N;
        #pragma unroll
        for (int j = 0; j < 8; ++j) br[j] = bs[(size_t)j * N];
      }
      short8 af[4];
      #pragma unroll
      for (int mf = 0; mf < 4; ++mf)
        af[mf] = *(const short8*)(As + b * 8192 + aoff[mf]);
      #pragma unroll
      for (int nf = 0; nf < 2; ++nf) {
        short8 fg = *(const short8*)(Bls + b * 4608 + boff[nf]);
        short8 fu = *(const short8*)(Bls + b * 4608 + 2304 + boff[nf]);
        #pragma unroll
        for (int mf = 0; mf < 4; ++mf) {
          accg[mf][nf] = __builtin_amdgcn_mfma_f32_16x16x32_bf16(af[mf], fg, accg[mf][nf], 0, 0, 0);
          accu[mf][nf] = __builtin_amdgcn_mfma_f32_16x16x32_bf16(af[mf], fu, accu[mf][nf], 0, 0, 0);
        }
      }
      __syncthreads();
      b ^= 1;
    }

    // epilogue: silu(g)*u -> h in tile-linear layout (down-pass A format)
    unsigned short* hch = hbase + (size_t)ch * NKT_H * 8192;
    int m0 = ch * 256;
    #pragma unroll
    for (int mf = 0; mf < 4; ++mf)
      #pragma unroll
      for (int nf = 0; nf < 2; ++nf)
        #pragma unroll
        for (int v = 0; v < 4; ++v) {
          int mrow = wr * 64 + mf * 16 + r * 4 + v;
          if (m0 + mrow < nrows) {
            int col = n0 + wc * 32 + nf * 16 + c;
            float g = accg[mf][nf][v], u = accu[mf][nf][v];
            float s = g / (1.f + __expf(-g));
            hch[(size_t)(col >> 5) * 8192 + (((col >> 3) & 3) * 256 + mrow) * 8 + (col & 7)] =
                f2b(s * u);
          }
        }
  }
}

template<int NKT>
__device__ __forceinline__ void dn_body(
    const unsigned short* __restrict__ Abase,    // chunk stride NKT*8192
    const float* __restrict__ wdp,
    const int* __restrict__ tokp, const float* __restrict__ wtsp, float scale,
    float* __restrict__ out,
    int c0, int c1, int nrows, int n0,
    unsigned short* As, unsigned short* Bls)
{
  const int tid = threadIdx.x;
  const int wid = tid >> 6, lane = tid & 63;
  const int c = lane & 15, r = lane >> 4;
  const int wr = wid >> 1, wc = wid & 1;

  const int bko = wid & 3;
  const int half = wid >> 2;
  const float* bsrc = wdp + (size_t)(bko * 8 + half * 4) * D_HID + n0 + lane;
  const int bwoff = lane * 36 + bko * 8 + half * 4;

  int aoff[4];
  #pragma unroll
  for (int mf = 0; mf < 4; ++mf)
    aoff[mf] = (r * 256 + wr * 64 + mf * 16 + c) * 8;
  int boff[2];
  #pragma unroll
  for (int nf = 0; nf < 2; ++nf)
    boff[nf] = (wc * 32 + nf * 16 + c) * 36 + r * 8;

  for (int ch = c0; ch < c1; ++ch) {
    const unsigned short* Ach = Abase + (size_t)ch * NKT * 8192;

    floatx4 acc[4][2] = {};
    float br[4];

    #pragma unroll
    for (int j = 0; j < 4; ++j) br[j] = bsrc[(size_t)j * D_HID];
    { uint2 pw = pack4(br); *(uint2*)&Bls[bwoff] = pw; }
    gld_lds16(Ach + tid * 8, As + tid * 8);
    gld_lds16(Ach + (512 + tid) * 8, As + (512 + tid) * 8);
    #pragma unroll
    for (int j = 0; j < 4; ++j) br[j] = bsrc[(size_t)(32 + j) * D_HID];
    __syncthreads();

    int b = 0;
    for (int kt = 0; kt < NKT; ++kt) {
      if (kt + 1 < NKT) {
        { uint2 pw = pack4(br); *(uint2*)&Bls[(b ^ 1) * 2304 + bwoff] = pw; }
        const unsigned short* Ak = Ach + (size_t)(kt + 1) * 8192;
        gld_lds16(Ak + tid * 8, As + (b ^ 1) * 8192 + tid * 8);
        gld_lds16(Ak + (512 + tid) * 8, As + (b ^ 1) * 8192 + (512 + tid) * 8);
      }
      if (kt + 2 < NKT) {
        const float* bs = bsrc + (size_t)(kt + 2) * 32 * D_HID;
        #pragma unroll
        for (int j = 0; j < 4; ++j) br[j] = bs[(size_t)j * D_HID];
      }
      short8 af[4];
      #pragma unroll
      for (int mf = 0; mf < 4; ++mf)
        af[mf] = *(const short8*)(As + b * 8192 + aoff[mf]);
      #pragma unroll
      for (int nf = 0; nf < 2; ++nf) {
        short8 fd = *(const short8*)(Bls + b * 2304 + boff[nf]);
        #pragma unroll
        for (int mf = 0; mf < 4; ++mf)
          acc[mf][nf] = __builtin_amdgcn_mfma_f32_16x16x32_bf16(af[mf], fd, acc[mf][nf], 0, 0, 0);
      }
      __syncthreads();
      b ^= 1;
    }

    int m0 = ch * 256;
    #pragma unroll
    for (int mf = 0; mf < 4; ++mf)
      #pragma unroll
      for (int nf = 0; nf < 2; ++nf)
        #pragma unroll
        for (int v = 0; v < 4; ++v) {
          int mrow = wr * 64 + mf * 16 + r * 4 + v;
          if (m0 + mrow < nrows) {
            int grow = m0 + mrow;
            int tk = tokp ? tokp[grow] : grow;
            float w = wtsp ? wtsp[grow] * scale : scale;
            atomicAdd(&out[(size_t)tk * D_HID + n0 + wc * 32 + nf * 16 + c],
                      w * acc[mf][nf][v]);
          }
        }
  }
}

// flat grid: bid<176 -> shared (44 n-tiles x 4 chunks, dispatched first);
// else routed: e=(bid-176)/22, x=(bid-176)%22, in-body chunk loop.
__global__ __launch_bounds__(512, 4) void k_gu9(
    const unsigned short* __restrict__ Ap, const unsigned short* __restrict__ ApS,
    const float* __restrict__ wg, const float* __restrict__ wu,
    const float* __restrict__ wsg, const float* __restrict__ wsu,
    const int* __restrict__ cnt, const int* __restrict__ poff,
    unsigned short* __restrict__ hR, unsigned short* __restrict__ hS)
{
  __shared__ __align__(16) unsigned short As[2 * 8192];
  __shared__ __align__(16) unsigned short Bls[2 * 4608];
  int bid = blockIdx.x;
  if (bid < 176) {
    int x = bid % 44, ch = bid / 44;
    gu_body<SHI, 88>(ApS, wsg, wsu, hS, ch, ch + 1, T_TOK, x * 64, As, Bls);
  } else {
    int rel = bid - 176;
    int e = rel / 22, x = rel % 22;
    int nr = cnt[e];
    if (nr <= 0) return;
    int cb = poff[e] >> 8;
    gu_body<I_EXP, 44>(Ap + (size_t)cb * 64 * 8192,
                       wg + (size_t)e * D_HID * I_EXP,
                       wu + (size_t)e * D_HID * I_EXP,
                       hR + (size_t)cb * 44 * 8192,
                       0, (nr + 255) >> 8, nr, x * 64, As, Bls);
  }
}

// flat grid: bid<128 -> shared (32 n-tiles x 4 chunks); else routed.
__global__ __launch_bounds__(512, 4) void k_dn9(
    const unsigned short* __restrict__ hR, const unsigned short* __restrict__ hS,
    const float* __restrict__ wd, const float* __restrict__ wsd,
    const int* __restrict__ offp, const int* __restrict__ cnt,
    const int* __restrict__ poff,
    const int* __restrict__ tok, const float* __restrict__ wts,
    float* __restrict__ out)
{
  __shared__ __align__(16) unsigned short As[2 * 8192];
  __shared__ __align__(16) unsigned short Bls[2 * 2304];
  int bid = blockIdx.x;
  if (bid < 128) {
    int x = bid & 31, ch = bid >> 5;
    dn_body<88>(hS, wsd, nullptr, nullptr, 1.0f, out, ch, ch + 1, T_TOK, x * 64, As, Bls);
  } else {
    int rel = bid - 128;
    int e = rel >> 5, x = rel & 31;
    int nr = cnt[e];
    if (nr <= 0) return;
    int cb = poff[e] >> 8;
    dn_body<44>(hR + (size_t)cb * 44 * 8192,
                wd + (size_t)e * I_EXP * D_HID,
                tok + offp[e], wts + offp[e], RSCALE,
                out, 0, (nr + 255) >> 8, nr, x * 64, As, Bls);
  }
}

extern "C" void kernel_launch(void* const* d_in, const int* in_sizes, int n_in,
                              void* d_out, int out_size, void* d_ws, size_t ws_size,
                              hipStream_t stream) {
  const float* x    = (const float*)d_in[0];
  const float* gw   = (const float*)d_in[1];
  const float* bias = (const float*)d_in[2];
  const float* wg   = (const float*)d_in[3];
  const float* wu   = (const float*)d_in[4];
  const float* wd   = (const float*)d_in[5];
  const float* wsg  = (const float*)d_in[6];
  const float* wsu  = (const float*)d_in[7];
  const float* wsd  = (const float*)d_in[8];
  float* out = (float*)d_out;

  char* ws = (char*)d_ws;
  size_t o = 0;
  auto take = [&](size_t bytes) {
    char* p = ws + o;
    o += (bytes + 255) & ~(size_t)255;
    return p;
  };
  int*   tki  = (int*)  take((size_t)T_TOK * TOPK * 4);
  float* tkw  = (float*)take((size_t)T_TOK * TOPK * 4);
  int*   cnt  = (int*)  take(NEXP * 4);
  int*   offp = (int*)  take((NEXP + 1) * 4);
  int*   poff = (int*)  take((NEXP + 1) * 4);
  int*   tok  = (int*)  take((size_t)T_TOK * TOPK * 4);
  float* wts  = (float*)take((size_t)T_TOK * TOPK * 4);
  // worst-case padded rows: 6144 + 32*255 -> 14336
  unsigned short* Ap  = (unsigned short*)take((size_t)14336 * D_HID * 2);
  unsigned short* ApS = (unsigned short*)take((size_t)4 * 64 * 8192 * 2);
  unsigned short* hR  = (unsigned short*)take((size_t)56 * 44 * 8192 * 2);
  unsigned short* hS  = (unsigned short*)take((size_t)4 * 88 * 8192 * 2);

  (void)hipMemsetAsync(out, 0, (size_t)T_TOK * D_HID * sizeof(float), stream);
  k_route<<<T_TOK, 64, 0, stream>>>(x, gw, bias, tki, tkw);
  k_count<<<1, 256, 0, stream>>>(tki, cnt, offp, poff);
  k_compact<<<NEXP, 64, 0, stream>>>(tki, tkw, offp, tok, wts);
  k_prep<<<dim3(NEXP + 1, 4), 256, 0, stream>>>(x, offp, cnt, poff, tok, Ap, ApS);

  k_gu9<<<176 + 22 * NEXP, 512, 0, stream>>>(
      Ap, ApS, wg, wu, wsg, wsu, cnt, poff, hR, hS);
  k_dn9<<<128 + 32 * NEXP, 512, 0, stream>>>(
      hR, hS, wd, wsd, offp, cnt, poff, tok, wts, out);
}